// Round 1
// baseline (6296.690 us; speedup 1.0000x reference)
//
#include <hip/hip_runtime.h>
#include <math.h>

#define NN 100000
#define NE 3200000
#define D 64
#define H 4096
#define H3 12288

// ---------------- degrees ----------------
__global__ __launch_bounds__(256) void deg_kernel(const int* __restrict__ src,
                                                  const int* __restrict__ dst,
                                                  float* __restrict__ outdeg,
                                                  float* __restrict__ indeg) {
    int e = blockIdx.x * 256 + threadIdx.x;
    if (e < NE) {
        unsafeAtomicAdd(&outdeg[src[e]], 1.0f);
        unsafeAtomicAdd(&indeg[dst[e]], 1.0f);
    }
}

__global__ __launch_bounds__(256) void norm_kernel(float* __restrict__ v, int n) {
    int i = blockIdx.x * 256 + threadIdx.x;
    if (i < n) v[i] = rsqrtf(fmaxf(v[i], 1.0f));
}

// ---------------- GRU: fused matvec for both cells ----------------
// For row r in [0,3H): gi1[r]=Wih[r,:]·pg1+bih[r]; gh1[r]=Whh[r,:]·g1w+bhh[r];
//                      gi2[r]=Wih[r,:]·pg2+bih[r]; gh2[r]=Whh[r,:]·g2w+bhh[r].
// Reads each weight row ONCE for both cells.
__global__ __launch_bounds__(256) void gru_matvec(
    const float* __restrict__ Wih, const float* __restrict__ Whh,
    const float* __restrict__ bih, const float* __restrict__ bhh,
    const float* __restrict__ pg1, const float* __restrict__ pg2,
    const float* __restrict__ g1w, const float* __restrict__ g2w,
    float* __restrict__ gi1, float* __restrict__ gh1,
    float* __restrict__ gi2, float* __restrict__ gh2) {
    int r = blockIdx.x;
    int tid = threadIdx.x;
    const float4* wi = (const float4*)(Wih + (size_t)r * H);
    const float4* wh = (const float4*)(Whh + (size_t)r * H);
    const float4* x1 = (const float4*)pg1;
    const float4* x2 = (const float4*)pg2;
    const float4* h1 = (const float4*)g1w;
    const float4* h2 = (const float4*)g2w;
    float a0 = 0.f, a1 = 0.f, a2 = 0.f, a3 = 0.f;
    for (int k = tid; k < H / 4; k += 256) {
        float4 wiv = wi[k];
        float4 whv = wh[k];
        float4 v1 = x1[k], v2 = x2[k], u1 = h1[k], u2 = h2[k];
        a0 += wiv.x * v1.x + wiv.y * v1.y + wiv.z * v1.z + wiv.w * v1.w;
        a1 += whv.x * u1.x + whv.y * u1.y + whv.z * u1.z + whv.w * u1.w;
        a2 += wiv.x * v2.x + wiv.y * v2.y + wiv.z * v2.z + wiv.w * v2.w;
        a3 += whv.x * u2.x + whv.y * u2.y + whv.z * u2.z + whv.w * u2.w;
    }
    // wave64 shuffle reduce
    for (int off = 32; off; off >>= 1) {
        a0 += __shfl_down(a0, off);
        a1 += __shfl_down(a1, off);
        a2 += __shfl_down(a2, off);
        a3 += __shfl_down(a3, off);
    }
    __shared__ float red[4][4];  // [wave][acc]
    int wv = tid >> 6;
    if ((tid & 63) == 0) {
        red[wv][0] = a0; red[wv][1] = a1; red[wv][2] = a2; red[wv][3] = a3;
    }
    __syncthreads();
    if (tid < 4) {
        float s = red[0][tid] + red[1][tid] + red[2][tid] + red[3][tid];
        if (tid == 0)      gi1[r] = s + bih[r];
        else if (tid == 1) gh1[r] = s + bhh[r];
        else if (tid == 2) gi2[r] = s + bih[r];
        else               gh2[r] = s + bhh[r];
    }
}

__global__ __launch_bounds__(256) void gru_combine(
    const float* __restrict__ gi1, const float* __restrict__ gh1,
    const float* __restrict__ gi2, const float* __restrict__ gh2,
    const float* __restrict__ g1w, const float* __restrict__ g2w,
    float* __restrict__ w1, float* __restrict__ w2) {
    int gid = blockIdx.x * 256 + threadIdx.x;
    if (gid >= 2 * H) return;
    int c = gid >> 12;          // /H
    int j = gid & (H - 1);
    const float* gi = c ? gi2 : gi1;
    const float* gh = c ? gh2 : gh1;
    float hprev = c ? g2w[j] : g1w[j];
    float r = 1.f / (1.f + expf(-(gi[j] + gh[j])));
    float z = 1.f / (1.f + expf(-(gi[H + j] + gh[H + j])));
    float n = tanhf(gi[2 * H + j] + r * gh[2 * H + j]);
    float w = (1.f - z) * n + z * hprev;
    (c ? w2 : w1)[j] = w;
}

// ---------------- edge gather + scatter-add ----------------
// 16 threads per edge, float4 each. agg[dst] += x[src]*out_norm[src]
__global__ __launch_bounds__(256) void gather_scatter(
    const int* __restrict__ src, const int* __restrict__ dst,
    const float* __restrict__ x, const float* __restrict__ out_norm,
    float* __restrict__ agg) {
    long long gid = (long long)blockIdx.x * 256 + threadIdx.x;
    int e = (int)(gid >> 4);
    if (e >= NE) return;
    int c = ((int)gid & 15) << 2;
    int s = src[e], d = dst[e];
    float on = out_norm[s];
    float4 v = *(const float4*)(x + (size_t)s * D + c);
    float* ap = agg + (size_t)d * D + c;
    unsafeAtomicAdd(ap + 0, v.x * on);
    unsafeAtomicAdd(ap + 1, v.y * on);
    unsafeAtomicAdd(ap + 2, v.z * on);
    unsafeAtomicAdd(ap + 3, v.w * on);
}

// ---------------- per-layer GEMM: out = act(in_norm[i]*(agg @ W) + b) ----------------
__global__ __launch_bounds__(256) void gcn_gemm(
    const float* __restrict__ agg, const float* __restrict__ W,
    const float* __restrict__ bias, const float* __restrict__ in_norm,
    float* __restrict__ out, int relu) {
    __shared__ float sW[D * D];
    int tid = threadIdx.x;
    for (int i = tid; i < D * D; i += 256) sW[i] = W[i];
    __syncthreads();
    int row = blockIdx.x * 4 + (tid >> 6);
    int j = tid & 63;
    if (row >= NN) return;
    const float* arow = agg + (size_t)row * D;
    float acc = 0.f;
#pragma unroll
    for (int k = 0; k < D; ++k) acc += arow[k] * sW[k * D + j];
    float v = in_norm[row] * acc + bias[j];
    if (relu) v = fmaxf(v, 0.f);
    out[(size_t)row * D + j] = v;
}

extern "C" void kernel_launch(void* const* d_in, const int* in_sizes, int n_in,
                              void* d_out, int out_size, void* d_ws, size_t ws_size,
                              hipStream_t stream) {
    const float* x0   = (const float*)d_in[0];   // node_embeddings [NN*D]
    const float* gc1w = (const float*)d_in[1];   // [D*D] = H
    const float* gc2w = (const float*)d_in[2];
    const float* gc1b = (const float*)d_in[3];   // [D]
    const float* gc2b = (const float*)d_in[4];
    const float* pg1  = (const float*)d_in[5];   // [H]
    const float* pg2  = (const float*)d_in[6];
    const float* Wih  = (const float*)d_in[7];   // [3H*H]
    const float* Whh  = (const float*)d_in[8];
    const float* bih  = (const float*)d_in[9];   // [3H]
    const float* bhh  = (const float*)d_in[10];
    const int*   src  = (const int*)d_in[11];    // [NE]
    const int*   dst  = (const int*)d_in[12];
    float* out = (float*)d_out;
    float* ws  = (float*)d_ws;

    // workspace layout (floats)
    float* outn   = ws;                 // NN   (deg -> norm in place)
    float* innorm = ws + NN;            // NN
    float* w1  = ws + 200000;           // H
    float* w2  = w1 + H;                // H
    float* gi1 = w2 + H;                // 3H
    float* gh1 = gi1 + H3;              // 3H
    float* gi2 = gh1 + H3;              // 3H
    float* gh2 = gi2 + H3;              // 3H
    float* agg = ws + 262144;           // NN*D = 6.4M floats

    // degrees + norms
    hipMemsetAsync(outn, 0, (size_t)2 * NN * sizeof(float), stream);
    deg_kernel<<<(NE + 255) / 256, 256, 0, stream>>>(src, dst, outn, innorm);
    norm_kernel<<<(2 * NN + 255) / 256, 256, 0, stream>>>(outn, 2 * NN);

    // GRU weight evolution (both cells fused)
    gru_matvec<<<H3, 256, 0, stream>>>(Wih, Whh, bih, bhh, pg1, pg2, gc1w, gc2w,
                                       gi1, gh1, gi2, gh2);
    gru_combine<<<(2 * H + 255) / 256, 256, 0, stream>>>(gi1, gh1, gi2, gh2,
                                                         gc1w, gc2w, w1, w2);

    // layer 1: agg = scatter(x0*outn); h1 = relu(innorm*agg@w1 + b1) -> out
    hipMemsetAsync(agg, 0, (size_t)NN * D * sizeof(float), stream);
    gather_scatter<<<(NE * 16) / 256, 256, 0, stream>>>(src, dst, x0, outn, agg);
    gcn_gemm<<<NN / 4, 256, 0, stream>>>(agg, w1, gc1b, innorm, out, 1);

    // layer 2: agg = scatter(h1*outn); out = innorm*agg@w2 + b2
    hipMemsetAsync(agg, 0, (size_t)NN * D * sizeof(float), stream);
    gather_scatter<<<(NE * 16) / 256, 256, 0, stream>>>(src, dst, out, outn, agg);
    gcn_gemm<<<NN / 4, 256, 0, stream>>>(agg, w2, gc2b, innorm, out, 0);
}

// Round 2
// 1427.785 us; speedup vs baseline: 4.4101x; 4.4101x over previous
//
#include <hip/hip_runtime.h>
#include <math.h>

#define NN 100000
#define NE 3200000
#define D 64
#define H 4096
#define H3 12288
#define NB 391  // (NN+255)/256

// ---------------- degree counting (int) ----------------
__global__ __launch_bounds__(256) void deg_kernel(const int* __restrict__ src,
                                                  const int* __restrict__ dst,
                                                  int* __restrict__ outcnt,
                                                  int* __restrict__ incnt) {
    int e = blockIdx.x * 256 + threadIdx.x;
    if (e < NE) {
        atomicAdd(&outcnt[src[e]], 1);
        atomicAdd(&incnt[dst[e]], 1);
    }
}

__global__ __launch_bounds__(256) void norm_kernel(const int* __restrict__ outcnt,
                                                   const int* __restrict__ incnt,
                                                   float* __restrict__ outn,
                                                   float* __restrict__ innorm) {
    int i = blockIdx.x * 256 + threadIdx.x;
    if (i < NN) {
        outn[i]   = rsqrtf(fmaxf((float)outcnt[i], 1.0f));
        innorm[i] = rsqrtf(fmaxf((float)incnt[i],  1.0f));
    }
}

// ---------------- exclusive scan of incnt -> rowptr, cursor ----------------
__global__ __launch_bounds__(256) void scan_blocksums(const int* __restrict__ incnt,
                                                      int* __restrict__ bsums) {
    __shared__ int s[256];
    int t = threadIdx.x;
    int i = blockIdx.x * 256 + t;
    s[t] = (i < NN) ? incnt[i] : 0;
    __syncthreads();
    for (int off = 128; off; off >>= 1) {
        if (t < off) s[t] += s[t + off];
        __syncthreads();
    }
    if (t == 0) bsums[blockIdx.x] = s[0];
}

__global__ __launch_bounds__(512) void scan_partials(int* __restrict__ bsums) {
    __shared__ int s[512];
    int t = threadIdx.x;
    s[t] = (t < NB) ? bsums[t] : 0;
    __syncthreads();
    for (int off = 1; off < 512; off <<= 1) {
        int v = (t >= off) ? s[t - off] : 0;
        __syncthreads();
        s[t] += v;
        __syncthreads();
    }
    if (t < NB) bsums[t] = (t == 0) ? 0 : s[t - 1];  // exclusive
}

__global__ __launch_bounds__(256) void scan_write(const int* __restrict__ incnt,
                                                  const int* __restrict__ bsums,
                                                  int* __restrict__ rowptr,
                                                  int* __restrict__ cursor) {
    __shared__ int s[256];
    int t = threadIdx.x;
    int i = blockIdx.x * 256 + t;
    int c = (i < NN) ? incnt[i] : 0;
    s[t] = c;
    __syncthreads();
    for (int off = 1; off < 256; off <<= 1) {
        int v = (t >= off) ? s[t - off] : 0;
        __syncthreads();
        s[t] += v;
        __syncthreads();
    }
    int excl = s[t] - c + bsums[blockIdx.x];
    if (i < NN) { rowptr[i] = excl; cursor[i] = excl; }
    if (i == 0) rowptr[NN] = NE;
}

__global__ __launch_bounds__(256) void csr_fill(const int* __restrict__ src,
                                                const int* __restrict__ dst,
                                                int* __restrict__ cursor,
                                                int* __restrict__ csr_src) {
    int e = blockIdx.x * 256 + threadIdx.x;
    if (e < NE) {
        int pos = atomicAdd(&cursor[dst[e]], 1);
        csr_src[pos] = src[e];
    }
}

// ---------------- GRU: fused matvec for both cells ----------------
__global__ __launch_bounds__(256) void gru_matvec(
    const float* __restrict__ Wih, const float* __restrict__ Whh,
    const float* __restrict__ bih, const float* __restrict__ bhh,
    const float* __restrict__ pg1, const float* __restrict__ pg2,
    const float* __restrict__ g1w, const float* __restrict__ g2w,
    float* __restrict__ gi1, float* __restrict__ gh1,
    float* __restrict__ gi2, float* __restrict__ gh2) {
    int r = blockIdx.x;
    int tid = threadIdx.x;
    const float4* wi = (const float4*)(Wih + (size_t)r * H);
    const float4* wh = (const float4*)(Whh + (size_t)r * H);
    const float4* x1 = (const float4*)pg1;
    const float4* x2 = (const float4*)pg2;
    const float4* h1 = (const float4*)g1w;
    const float4* h2 = (const float4*)g2w;
    float a0 = 0.f, a1 = 0.f, a2 = 0.f, a3 = 0.f;
    for (int k = tid; k < H / 4; k += 256) {
        float4 wiv = wi[k];
        float4 whv = wh[k];
        float4 v1 = x1[k], v2 = x2[k], u1 = h1[k], u2 = h2[k];
        a0 += wiv.x * v1.x + wiv.y * v1.y + wiv.z * v1.z + wiv.w * v1.w;
        a1 += whv.x * u1.x + whv.y * u1.y + whv.z * u1.z + whv.w * u1.w;
        a2 += wiv.x * v2.x + wiv.y * v2.y + wiv.z * v2.z + wiv.w * v2.w;
        a3 += whv.x * u2.x + whv.y * u2.y + whv.z * u2.z + whv.w * u2.w;
    }
    for (int off = 32; off; off >>= 1) {
        a0 += __shfl_down(a0, off);
        a1 += __shfl_down(a1, off);
        a2 += __shfl_down(a2, off);
        a3 += __shfl_down(a3, off);
    }
    __shared__ float red[4][4];
    int wv = tid >> 6;
    if ((tid & 63) == 0) {
        red[wv][0] = a0; red[wv][1] = a1; red[wv][2] = a2; red[wv][3] = a3;
    }
    __syncthreads();
    if (tid < 4) {
        float s = red[0][tid] + red[1][tid] + red[2][tid] + red[3][tid];
        if (tid == 0)      gi1[r] = s + bih[r];
        else if (tid == 1) gh1[r] = s + bhh[r];
        else if (tid == 2) gi2[r] = s + bih[r];
        else               gh2[r] = s + bhh[r];
    }
}

__global__ __launch_bounds__(256) void gru_combine(
    const float* __restrict__ gi1, const float* __restrict__ gh1,
    const float* __restrict__ gi2, const float* __restrict__ gh2,
    const float* __restrict__ g1w, const float* __restrict__ g2w,
    float* __restrict__ w1, float* __restrict__ w2) {
    int gid = blockIdx.x * 256 + threadIdx.x;
    if (gid >= 2 * H) return;
    int c = gid >> 12;
    int j = gid & (H - 1);
    const float* gi = c ? gi2 : gi1;
    const float* gh = c ? gh2 : gh1;
    float hprev = c ? g2w[j] : g1w[j];
    float r = 1.f / (1.f + expf(-(gi[j] + gh[j])));
    float z = 1.f / (1.f + expf(-(gi[H + j] + gh[H + j])));
    float n = tanhf(gi[2 * H + j] + r * gh[2 * H + j]);
    float w = (1.f - z) * n + z * hprev;
    (c ? w2 : w1)[j] = w;
}

// ---------------- layer 1: CSR aggregation + fused 64x64 GEMM ----------------
// one wave per dst node; lane j owns feature column j
__global__ __launch_bounds__(256) void agg_gemm_fused(
    const int* __restrict__ rowptr, const int* __restrict__ csr_src,
    const float* __restrict__ x, const float* __restrict__ outn,
    const float* __restrict__ innorm, const float* __restrict__ W,
    const float* __restrict__ bias, float* __restrict__ out) {
    __shared__ float sW[D * D];
    int tid = threadIdx.x;
    for (int i = tid; i < D * D; i += 256) sW[i] = W[i];
    __syncthreads();
    int node = blockIdx.x * 4 + (tid >> 6);
    int lane = tid & 63;
    if (node >= NN) return;
    int e = rowptr[node], end = rowptr[node + 1];
    float acc = 0.f;
    for (; e + 1 < end; e += 2) {
        int s0 = csr_src[e], s1 = csr_src[e + 1];
        float on0 = outn[s0], on1 = outn[s1];
        float v0 = x[(size_t)s0 * D + lane];
        float v1 = x[(size_t)s1 * D + lane];
        acc += v0 * on0 + v1 * on1;
    }
    if (e < end) {
        int s0 = csr_src[e];
        acc += x[(size_t)s0 * D + lane] * outn[s0];
    }
    acc *= innorm[node];
    float o = 0.f;
#pragma unroll
    for (int k = 0; k < D; ++k) {
        float ak = __shfl(acc, k);
        o += ak * sW[k * D + lane];
    }
    o += bias[lane];
    o = fmaxf(o, 0.f);  // relu
    out[(size_t)node * D + lane] = o;
}

// ---------------- layer 2: CSR aggregation only ----------------
__global__ __launch_bounds__(256) void agg_only(
    const int* __restrict__ rowptr, const int* __restrict__ csr_src,
    const float* __restrict__ x, const float* __restrict__ outn,
    float* __restrict__ agg) {
    int tid = threadIdx.x;
    int node = blockIdx.x * 4 + (tid >> 6);
    int lane = tid & 63;
    if (node >= NN) return;
    int e = rowptr[node], end = rowptr[node + 1];
    float acc = 0.f;
    for (; e + 1 < end; e += 2) {
        int s0 = csr_src[e], s1 = csr_src[e + 1];
        float on0 = outn[s0], on1 = outn[s1];
        float v0 = x[(size_t)s0 * D + lane];
        float v1 = x[(size_t)s1 * D + lane];
        acc += v0 * on0 + v1 * on1;
    }
    if (e < end) {
        int s0 = csr_src[e];
        acc += x[(size_t)s0 * D + lane] * outn[s0];
    }
    agg[(size_t)node * D + lane] = acc;
}

// ---------------- per-layer GEMM: out = in_norm[i]*(agg @ W) + b ----------------
__global__ __launch_bounds__(256) void gcn_gemm(
    const float* __restrict__ agg, const float* __restrict__ W,
    const float* __restrict__ bias, const float* __restrict__ in_norm,
    float* __restrict__ out, int relu) {
    __shared__ float sW[D * D];
    int tid = threadIdx.x;
    for (int i = tid; i < D * D; i += 256) sW[i] = W[i];
    __syncthreads();
    int row = blockIdx.x * 4 + (tid >> 6);
    int j = tid & 63;
    if (row >= NN) return;
    const float* arow = agg + (size_t)row * D;
    float acc = 0.f;
#pragma unroll
    for (int k = 0; k < D; ++k) acc += arow[k] * sW[k * D + j];
    float v = in_norm[row] * acc + bias[j];
    if (relu) v = fmaxf(v, 0.f);
    out[(size_t)row * D + j] = v;
}

extern "C" void kernel_launch(void* const* d_in, const int* in_sizes, int n_in,
                              void* d_out, int out_size, void* d_ws, size_t ws_size,
                              hipStream_t stream) {
    const float* x0   = (const float*)d_in[0];
    const float* gc1w = (const float*)d_in[1];
    const float* gc2w = (const float*)d_in[2];
    const float* gc1b = (const float*)d_in[3];
    const float* gc2b = (const float*)d_in[4];
    const float* pg1  = (const float*)d_in[5];
    const float* pg2  = (const float*)d_in[6];
    const float* Wih  = (const float*)d_in[7];
    const float* Whh  = (const float*)d_in[8];
    const float* bih  = (const float*)d_in[9];
    const float* bhh  = (const float*)d_in[10];
    const int*   src  = (const int*)d_in[11];
    const int*   dst  = (const int*)d_in[12];
    float* out = (float*)d_out;
    float* ws  = (float*)d_ws;

    // workspace layout (float offsets)
    float* outn   = ws;                         // NN
    float* innorm = ws + 100000;                // NN
    int* outcnt = (int*)(ws + 200000);          // NN
    int* incnt  = (int*)(ws + 300000);          // NN
    int* rowptr = (int*)(ws + 400000);          // NN+1
    int* cursor = (int*)(ws + 500004);          // NN
    int* bsums  = (int*)(ws + 600064);          // 512
    float* w1  = ws + 600576;                   // H
    float* w2  = w1 + H;
    float* gi1 = w2 + H;                        // 3H each
    float* gh1 = gi1 + H3;
    float* gi2 = gh1 + H3;
    float* gh2 = gi2 + H3;
    int* csr_src = (int*)(ws + 700000);         // NE
    float* agg   = ws + 3900000;                // NN*D

    // degrees + norms
    hipMemsetAsync(outcnt, 0, (size_t)2 * NN * sizeof(int), stream);
    deg_kernel<<<(NE + 255) / 256, 256, 0, stream>>>(src, dst, outcnt, incnt);
    norm_kernel<<<(NN + 255) / 256, 256, 0, stream>>>(outcnt, incnt, outn, innorm);

    // CSR build (by dst)
    scan_blocksums<<<NB, 256, 0, stream>>>(incnt, bsums);
    scan_partials<<<1, 512, 0, stream>>>(bsums);
    scan_write<<<NB, 256, 0, stream>>>(incnt, bsums, rowptr, cursor);
    csr_fill<<<(NE + 255) / 256, 256, 0, stream>>>(src, dst, cursor, csr_src);

    // GRU weight evolution (both cells fused)
    gru_matvec<<<H3, 256, 0, stream>>>(Wih, Whh, bih, bhh, pg1, pg2, gc1w, gc2w,
                                       gi1, gh1, gi2, gh2);
    gru_combine<<<(2 * H + 255) / 256, 256, 0, stream>>>(gi1, gh1, gi2, gh2,
                                                         gc1w, gc2w, w1, w2);

    // layer 1: fused aggregation + GEMM + relu -> d_out (h1)
    agg_gemm_fused<<<(NN + 3) / 4, 256, 0, stream>>>(rowptr, csr_src, x0, outn,
                                                     innorm, w1, gc1b, out);

    // layer 2: aggregation of h1 -> agg; then GEMM -> d_out
    agg_only<<<(NN + 3) / 4, 256, 0, stream>>>(rowptr, csr_src, out, outn, agg);
    gcn_gemm<<<(NN + 3) / 4, 256, 0, stream>>>(agg, w2, gc2b, innorm, out, 0);
}